// Round 7
// baseline (131.791 us; speedup 1.0000x reference)
//
#include <hip/hip_runtime.h>
#include <hip/hip_bf16.h>

// B=8, C=64, O=64, H=W=128, stride=1, pad=1, 3x3 periphery conv + mask + 1x1 matmul.
constexpr int Bc = 8;
constexpr int Cc = 64;
constexpr int Oc = 64;
constexpr int Hc = 128;
constexpr int Wc = 128;
constexpr int HWc = Hc * Wc;
constexpr int CP = 72;   // LDS row stride in bf16 (144 B): bank-coeff 4 -> w spreads banks

typedef __attribute__((ext_vector_type(8))) short short8;   // 8 bf16 (4 VGPRs)
typedef __attribute__((ext_vector_type(4))) short short4v;  // 4 bf16 (8 B)
typedef __attribute__((ext_vector_type(4))) float floatx4;

// XOR-swizzle bits 3..5 of the c index by the w sub-block to spread LDS banks.
// Stores (per-lane b16 runs over w) and MFMA b128 reads both land <=2-way (free).
__device__ __forceinline__ int swz(int wloc, int c) {
    return c ^ ((( wloc >> 2) & 7) << 3);
}

__device__ __forceinline__ short f2bf(float f) {
    __hip_bfloat16 h = __float2bfloat16(f);
    return *reinterpret_cast<short*>(&h);
}

// Pre-kernel: core fp32 [64x64] -> bf16 in ws (A-operand source, L2-hot).
__global__ __launch_bounds__(256) void core_cvt_kernel(
    const float* __restrict__ core, __hip_bfloat16* __restrict__ wsc)
{
    const int t = threadIdx.x;
    #pragma unroll
    for (int i = 0; i < 4; ++i) {
        const int e = (i * 256 + t) * 4;
        const floatx4 cv = *(const floatx4*)&core[e];
        short4v cv16 = { f2bf(cv.x), f2bf(cv.y), f2bf(cv.z), f2bf(cv.w) };
        *(short4v*)&wsc[e] = cv16;
    }
}

// STRUCTURE NOTE (R6 post-mortem): 1024 four-wave blocks with 2 barriers sat
// at 42-56 us with Occupancy ~10% / VALU 11% / HBM 12% -- all pipes idle,
// barrier+block-granularity latency-bound. This version: one WAVE per block
// (64 thr), 4096 independent blocks, __syncthreads on a 1-wave block is just
// a waitcnt. LDS 4.6 KB/block.
//
// Block = (b, h, w-quarter of 32). Lane = (wgrp=lane&7 -> 4 consecutive w,
// cidx=lane>>3). 8 rounds over channels c = r*8+cidx:
//   load 3 float4 rows; w+-1 via width-8 shuffles; tile-edge columns via
//   predicated scalar loads; agg -> LDS bf16 immediately (no big live set);
//   div partials accumulate in regs.
// Then: div reduced over cidx via 3 shfl_xor; mask; rare fixup reloads
// centers from global under exec mask; MFMA 2 w-tiles x 4 o-tiles x K=64
// with A-frags read as bf16 from ws.
__global__ __launch_bounds__(64) void spconv_kernel(
    const float* __restrict__ x, const __hip_bfloat16* __restrict__ wscore,
    const float* __restrict__ peri, const float* __restrict__ thr,
    const float* __restrict__ scl, float* __restrict__ out)
{
    __shared__ __hip_bfloat16 s_sel[32][CP];   // [w local][c swz] 4608 B

    const int lane = threadIdx.x;
    const int wgrp = lane & 7;
    const int cidx = lane >> 3;

    const int blk = blockIdx.x;
    const int q   = blk & 3;
    const int h   = (blk >> 2) & (Hc - 1);
    const int b   = blk >> 9;
    const int w0  = q * 32;              // tile base in image w
    const int wl  = wgrp * 4;            // lane's local 4-w base

    const float thr0 = thr[0], scl0 = scl[0];
    float p[8];
    #pragma unroll
    for (int k = 0; k < 8; ++k) p[k] = peri[k];

    const float* xb = x + (size_t)b * Cc * HWc + (size_t)h * Wc + w0;
    const bool hm = (h > 0), hp = (h < Hc - 1);
    const bool lim = (w0 == 0), rim = (w0 + 32 == Wc);
    const floatx4 zero4 = {0.f, 0.f, 0.f, 0.f};

    float div4[4] = {0.f, 0.f, 0.f, 0.f};

    #pragma unroll
    for (int r = 0; r < 8; ++r) {
        const int c = r * 8 + cidx;
        const float* row = xb + (size_t)c * HWc + wl;   // &x[b,c,h,w0+wl]

        const floatx4 tc = hm ? *(const floatx4*)(row - Wc) : zero4;
        const floatx4 mc =      *(const floatx4*)(row);
        const floatx4 bc = hp ? *(const floatx4*)(row + Wc) : zero4;

        // neighbors across 4-w blocks: width-8 shuffle groups == cidx groups
        float tl = __shfl_up(tc.w, 1, 8),  tr = __shfl_down(tc.x, 1, 8);
        float ml = __shfl_up(mc.w, 1, 8),  mr = __shfl_down(mc.x, 1, 8);
        float bl = __shfl_up(bc.w, 1, 8),  br = __shfl_down(bc.x, 1, 8);

        // tile-edge columns (rare lanes): real values unless at image edge
        if (wgrp == 0) {
            tl = 0.f; ml = 0.f; bl = 0.f;
            if (!lim) {
                const float* e = xb + (size_t)c * HWc - 1;
                ml = e[0];
                if (hm) tl = e[-Wc];
                if (hp) bl = e[Wc];
            }
        }
        if (wgrp == 7) {
            tr = 0.f; mr = 0.f; br = 0.f;
            if (!rim) {
                const float* e = xb + (size_t)c * HWc + 32;
                mr = e[0];
                if (hm) tr = e[-Wc];
                if (hp) br = e[Wc];
            }
        }

        const float top[6] = {tl, tc.x, tc.y, tc.z, tc.w, tr};
        const float mid[6] = {ml, mc.x, mc.y, mc.z, mc.w, mr};
        const float bot[6] = {bl, bc.x, bc.y, bc.z, bc.w, br};

        #pragma unroll
        for (int j = 0; j < 4; ++j) {
            const float t4 = mid[j + 1];
            float a = p[0] * top[j];
            a = fmaf(p[1], top[j + 1], a);
            a = fmaf(p[2], top[j + 2], a);
            a = fmaf(p[3], mid[j],     a);
            a = fmaf(p[4], mid[j + 2], a);
            a = fmaf(p[5], bot[j],     a);
            a = fmaf(p[6], bot[j + 1], a);
            a = fmaf(p[7], bot[j + 2], a);
            s_sel[wl + j][swz(wl + j, c)] = __float2bfloat16(a);

            float s = div4[j], d;
            d = top[j]     - t4; s = fmaf(d, d, s);
            d = top[j + 1] - t4; s = fmaf(d, d, s);
            d = top[j + 2] - t4; s = fmaf(d, d, s);
            d = mid[j]     - t4; s = fmaf(d, d, s);
            d = mid[j + 2] - t4; s = fmaf(d, d, s);
            d = bot[j]     - t4; s = fmaf(d, d, s);
            d = bot[j + 1] - t4; s = fmaf(d, d, s);
            d = bot[j + 2] - t4; s = fmaf(d, d, s);
            div4[j] = s;
        }
    }

    // ---- div reduce over cidx (lanes stride 8) + mask ----
    bool m[4];
    #pragma unroll
    for (int j = 0; j < 4; ++j) {
        float d = div4[j];
        d += __shfl_xor(d, 8);
        d += __shfl_xor(d, 16);
        d += __shfl_xor(d, 32);
        m[j] = ((d - thr0) * scl0) > 0.f;
    }

    // ---- rare fixup: sel[:,w] = center where mask==0 ----
    if (!(m[0] && m[1] && m[2] && m[3])) {
        for (int r = 0; r < 8; ++r) {
            const int c = r * 8 + cidx;
            const float* row = xb + (size_t)c * HWc + wl;
            #pragma unroll
            for (int j = 0; j < 4; ++j)
                if (!m[j]) s_sel[wl + j][swz(wl + j, c)] = __float2bfloat16(row[j]);
        }
    }
    __syncthreads();   // single wave: ~just s_waitcnt lgkmcnt(0)

    // ---- MFMA: D[o][w] = core[o][c] * sel[c][w], 2 w-tiles x 4 o-tiles, K=64
    const int n    = lane & 15;
    const int quad = lane >> 4;

    short8 A[4][2];
    #pragma unroll
    for (int t = 0; t < 4; ++t)
        #pragma unroll
        for (int s = 0; s < 2; ++s)
            A[t][s] = *(const short8*)&wscore[(t * 16 + n) * 64 + s * 32 + quad * 8];

    float* ob = out + ((size_t)(b * Oc) * Hc + h) * Wc + w0;

    #pragma unroll
    for (int wt = 0; wt < 2; ++wt) {
        const int wloc = wt * 16 + n;
        const int g = (wloc >> 2) & 7;
        const short8 B0 = *(const short8*)&s_sel[wloc][((0 * 4 + quad) ^ g) * 8];
        const short8 B1 = *(const short8*)&s_sel[wloc][((1 * 4 + quad) ^ g) * 8];
        #pragma unroll
        for (int t = 0; t < 4; ++t) {
            floatx4 acc = {0.f, 0.f, 0.f, 0.f};
            acc = __builtin_amdgcn_mfma_f32_16x16x32_bf16(A[t][0], B0, acc, 0, 0, 0);
            acc = __builtin_amdgcn_mfma_f32_16x16x32_bf16(A[t][1], B1, acc, 0, 0, 0);
            #pragma unroll
            for (int rr = 0; rr < 4; ++rr) {
                const int o = t * 16 + quad * 4 + rr;
                ob[(size_t)o * HWc + wloc] = acc[rr];
            }
        }
    }
}

extern "C" void kernel_launch(void* const* d_in, const int* in_sizes, int n_in,
                              void* d_out, int out_size, void* d_ws, size_t ws_size,
                              hipStream_t stream) {
    const float* x    = (const float*)d_in[0];
    const float* core = (const float*)d_in[1];
    const float* peri = (const float*)d_in[2];
    const float* thr  = (const float*)d_in[3];
    const float* scl  = (const float*)d_in[4];
    float* out = (float*)d_out;
    __hip_bfloat16* wsc = (__hip_bfloat16*)d_ws;

    core_cvt_kernel<<<dim3(1), dim3(256), 0, stream>>>(core, wsc);
    spconv_kernel<<<dim3(Bc * Hc * 4), dim3(64), 0, stream>>>(
        x, wsc, peri, thr, scl, out);
}